// Round 6
// baseline (1532.193 us; speedup 1.0000x reference)
//
#include <hip/hip_runtime.h>
#include <hip/hip_bf16.h>
#include <math.h>

#define BB   64
#define CC   862
#define FB   257
#define DM   256
#define DFF  512
#define NIMG 128
#define ROWS_RE (BB*CC)        // 55168
#define ROWS_ALL (NIMG*CC)     // 110336
#define NELEM ((long)ROWS_ALL*DM)  // 28,246,016

typedef __bf16 bf16x8 __attribute__((ext_vector_type(8)));
typedef float  f32x4  __attribute__((ext_vector_type(4)));

// ---------------- FF weights f32 -> bf16, once ------------------------------
__global__ __launch_bounds__(256) void k_wcvt(const float* __restrict__ W1,
                                              const float* __restrict__ W2,
                                              __bf16* __restrict__ W1b,
                                              __bf16* __restrict__ W2b) {
  long i = ((long)blockIdx.x * 256 + threadIdx.x) * 4;
  const long N1 = 3L * DFF * DM;   // 393216
  const float* src;
  __bf16* dst;
  if (i < N1) { src = W1 + i; dst = W1b + i; }
  else        { src = W2 + (i - N1); dst = W2b + (i - N1); }
  float4 x = *(const float4*)src;
  dst[0] = (__bf16)x.x; dst[1] = (__bf16)x.y;
  dst[2] = (__bf16)x.z; dst[3] = (__bf16)x.w;
}

__global__ void k_ident(float* ss) {
  int d = threadIdx.x;
  ss[d] = 1.0f;
  ss[DM + d] = 0.0f;
}

// ---------------- embedding weights -> bf16 B matrix [512][544] -------------
#define KE 544
#define PE 552

__global__ __launch_bounds__(256) void k_wemb(const float* __restrict__ Wre,
                                              const float* __restrict__ Wim,
                                              __bf16* __restrict__ Wb) {
  int n = blockIdx.x;          // 0..511
  int d = n & 255;
  bool im = (n >= 256);
  const float* Wa = im ? Wim : Wre;   // k<257 part
  const float* Wc = im ? Wre : Wim;   // k>=257 part
  float sgn = im ? 1.0f : -1.0f;
  for (int k = threadIdx.x; k < KE; k += 256) {
    float v;
    if (k < 257)      v = Wa[(long)d * FB + k];
    else if (k < 514) v = sgn * Wc[(long)d * FB + (k - 257)];
    else              v = 0.0f;
    Wb[(long)n * KE + k] = (__bf16)v;
  }
}

// ---------------- embedding as bf16 MFMA GEMM v3 -----------------------------
// 32 rows/block, 8 waves (512 thr); wave w owns output cols [w*64,(w+1)*64).
// LDS 32*552*2 = 34.5KB -> 4 blocks/CU x 8 waves = 2048 thr = 100% occupancy.
__global__ __launch_bounds__(512, 8) void k_embm(
    const float* __restrict__ xr, const float* __restrict__ xi,
    const __bf16* __restrict__ Wb,
    const float* __restrict__ bre, const float* __restrict__ bim,
    float* __restrict__ A) {
  __shared__ __bf16 sA[32 * PE];
  int t = threadIdx.x;
  int lane = t & 63;
  int w = t >> 6;           // 0..7
  int half = lane >> 4;     // 0..3
  int l16 = lane & 15;
  long row0 = (long)blockIdx.x * 32;

  // zero K-pad [514,544)
  for (int idx = t; idx < 32 * 30; idx += 512) {
    int r = idx / 30, j = idx - r * 30;
    sA[r * PE + 514 + j] = (__bf16)0.f;
  }
  // stage x tile: f32 -> bf16, xr at k<257, xi at 257+f
  for (int idx = t; idx < 32 * 257; idx += 512) {
    int r = idx / 257, f = idx - r * 257;
    long g = (row0 + r) * FB + f;
    sA[r * PE + f]       = (__bf16)xr[g];
    sA[r * PE + 257 + f] = (__bf16)xi[g];
  }
  __syncthreads();

  int n0 = w * 64;
  f32x4 acc[2][4];
#pragma unroll
  for (int mt = 0; mt < 2; mt++)
#pragma unroll
    for (int j = 0; j < 4; j++) acc[mt][j] = (f32x4){0.f, 0.f, 0.f, 0.f};

#pragma unroll 1
  for (int kt = 0; kt < 17; kt++) {
    int kb = kt * 32 + half * 8;
    bf16x8 a[2];
#pragma unroll
    for (int mt = 0; mt < 2; mt++)
      a[mt] = *(const bf16x8*)&sA[(mt * 16 + l16) * PE + kb];
#pragma unroll
    for (int j = 0; j < 4; j++) {
      bf16x8 bfr = *(const bf16x8*)&Wb[(long)(n0 + j * 16 + l16) * KE + kb];
#pragma unroll
      for (int mt = 0; mt < 2; mt++)
        acc[mt][j] = __builtin_amdgcn_mfma_f32_16x16x32_bf16(a[mt], bfr, acc[mt][j], 0, 0, 0);
    }
  }

  // epilogue: bias + store f32 (re half / im half of A)
#pragma unroll
  for (int j = 0; j < 4; j++) {
    int n = n0 + j * 16 + l16;
    int d = n & 255;
    float bv = (n < 256) ? bre[d] : bim[d];
    long rbase = (n < 256) ? 0L : (long)ROWS_RE;
#pragma unroll
    for (int mt = 0; mt < 2; mt++)
#pragma unroll
      for (int r = 0; r < 4; r++) {
        int m = mt * 16 + half * 4 + r;
        A[(row0 + m + rbase) * DM + d] = acc[mt][j][r] + bv;
      }
  }
}

// ---------------- attention + fused BN-apply on read + transpose-scramble ----
__global__ __launch_bounds__(256) void k_attn(const float* __restrict__ A,
                                              const float* __restrict__ ss,
                                              float* __restrict__ T) {
  __shared__ float ore[32][33];
  __shared__ float oim[32][33];
  __shared__ float ssc[256];
  __shared__ float ssh[256];
  int tx = threadIdx.x;
  int ty = threadIdx.y;
  int t = ty * 32 + tx;
  ssc[t] = ss[t];
  ssh[t] = ss[DM + t];
  __syncthreads();

  int c0 = blockIdx.x * 32;
  int d0 = blockIdx.y * 32;
  int b  = blockIdx.z;
  const long base_re = (long)b * CC * DM;
  const long base_im = (long)(b + BB) * CC * DM;
  int d = d0 + tx;
  int kd = DM - 1 - d;
  float scq = ssc[d], shq = ssh[d];
  float sck = ssc[kd], shk = ssh[kd];
#pragma unroll
  for (int q = 0; q < 4; q++) {
    int cl = ty + 8 * q;
    int c = c0 + cl;
    if (c < CC) {
      float qr = fmaf(A[base_re + (long)c * DM + d], scq, shq);
      float qi = fmaf(A[base_im + (long)c * DM + d], scq, shq);
      float kr = fmaf(A[base_re + (long)(CC - 1 - c) * DM + kd], sck, shk);
      float ki = fmaf(A[base_im + (long)(CC - 1 - c) * DM + kd], sck, shk);
      float asr = 0.25f * (qr * kr - qi * ki);
      float asi = 0.25f * (qr * ki - qi * kr);
      ore[cl][tx] = (asr - asi) * qr;
      oim[cl][tx] = (asr + asi) * qr;
    }
  }
  __syncthreads();
#pragma unroll
  for (int q = 0; q < 4; q++) {
    int dl = ty + 8 * q;
    int dd = d0 + dl;
    int c = c0 + tx;
    if (c < CC) {
      long flat = (long)dd * CC + c;
      int dp = (int)(flat & 255);
      float sc = ssc[dp], sh = ssh[dp];
      T[base_re + flat] = fmaf(A[base_re + flat], sc, sh) + ore[tx][dl];
      T[base_im + flat] = fmaf(A[base_im + flat], sc, sh) + oim[tx][dl];
    }
  }
}

// ---------------- batchnorm helpers ----------------
__global__ void k_zero(double* s) { s[threadIdx.x] = 0.0; }

__global__ __launch_bounds__(256) void k_bnstats(const float* __restrict__ P,
                                                 double* __restrict__ stats) {
  int d = threadIdx.x;
  long row0 = (long)blockIdx.x * 128;
  double s = 0.0, s2 = 0.0;
  for (int r = 0; r < 128; r++) {
    float x = P[(row0 + r) * DM + d];
    s += (double)x;
    s2 += (double)x * (double)x;
  }
  atomicAdd(&stats[d], s);
  atomicAdd(&stats[DM + d], s2);
}

// finalize + re-zero stats for the next accumulation pass
__global__ void k_finalize(double* __restrict__ stats,
                           const float* __restrict__ g, const float* __restrict__ be,
                           float* __restrict__ ss) {
  int d = threadIdx.x;
  double n = (double)ROWS_ALL;
  double m = stats[d] / n;
  double v = stats[DM + d] / n - m * m;
  float inv = (float)(1.0 / sqrt(v + 1e-5));
  float sc = g[d] * inv;
  ss[d] = sc;
  ss[DM + d] = be[d] - (float)m * sc;
  stats[d] = 0.0;
  stats[DM + d] = 0.0;
}

__global__ __launch_bounds__(256) void k_bnfinal(const float* __restrict__ A,
                                                 const float* __restrict__ ss,
                                                 float* __restrict__ out) {
  long gid = (long)blockIdx.x * 256 + threadIdx.x;
  int d = (int)(gid & 255);
  long bc = gid >> 8;
  float sc = ss[d], sh = ss[DM + d];
  float re = A[bc * DM + d];
  float im = A[(bc + (long)ROWS_RE) * DM + d];
  float2 o;
  o.x = fmaf(re, sc, sh);
  o.y = fmaf(im, sc, sh);
  ((float2*)out)[gid] = o;
}

// ---------------- MFMA fused FF v5 ------------------------------------------
// out = bn(src) + gelu(bn(src)@W1^T + b1)@W2^T + b2, plus atomic BN-stats of out.
// v5: 32 rows/block, 8 waves, F in two halves sharing one H buffer.
// LDS 2 x 32*268*2 = 34.3KB -> 4 blocks/CU x 512 thr = 100% occupancy
// (8 waves/SIMD, VGPR<=64 via launch_bounds). FF2 K-order unchanged.
#define PS2 268
#define PHH 268

__global__ __launch_bounds__(512, 8) void k_ffm(
    const float* __restrict__ P, const float* __restrict__ ss,
    const __bf16* __restrict__ W1b, const float* __restrict__ b1,
    const __bf16* __restrict__ W2b, const float* __restrict__ b2,
    float* __restrict__ Out, double* __restrict__ stats) {
  __shared__ __bf16 sS[32 * PS2];
  __shared__ __bf16 sH[32 * PHH];
  int t = threadIdx.x;
  int lane = t & 63;
  int w = t >> 6;           // 0..7
  int half = lane >> 4;     // 0..3
  int l16 = lane & 15;
  long row0 = (long)blockIdx.x * 32;

  // ---- stage S tile: f32 -> BN-apply -> bf16 ----
  {
    const float4* Pv = (const float4*)(P + row0 * DM);
    const float4* scv = (const float4*)ss;
    const float4* shv = (const float4*)(ss + DM);
#pragma unroll
    for (int i = 0; i < 4; i++) {
      int v = t + i * 512;        // 2048 float4s = 32 rows x 64
      int r = v >> 6, k4 = v & 63;
      float4 x = Pv[(long)r * 64 + k4];
      float4 sc = scv[k4];
      float4 sh = shv[k4];
      x.x = fmaf(x.x, sc.x, sh.x);
      x.y = fmaf(x.y, sc.y, sh.y);
      x.z = fmaf(x.z, sc.z, sh.z);
      x.w = fmaf(x.w, sc.w, sh.w);
      __bf16* dst = &sS[r * PS2 + k4 * 4];
      dst[0] = (__bf16)x.x; dst[1] = (__bf16)x.y;
      dst[2] = (__bf16)x.z; dst[3] = (__bf16)x.w;
    }
  }
  __syncthreads();

  int n2 = w * 32;
  f32x4 acc2[2][2];
#pragma unroll
  for (int mt = 0; mt < 2; mt++)
#pragma unroll
    for (int j = 0; j < 2; j++) acc2[mt][j] = (f32x4){0.f, 0.f, 0.f, 0.f};

#pragma unroll 1
  for (int hf = 0; hf < 2; hf++) {
    if (hf == 1) __syncthreads();   // all waves done reading sH(half A)

    // ---- FF1 half: H[:,fh] = gelu(S @ W1^T + b1)
    f32x4 acc[2][2];
#pragma unroll
    for (int mt = 0; mt < 2; mt++)
#pragma unroll
      for (int j = 0; j < 2; j++) acc[mt][j] = (f32x4){0.f, 0.f, 0.f, 0.f};

#pragma unroll 2
    for (int kt = 0; kt < 8; kt++) {
      int kb = kt * 32 + half * 8;
      bf16x8 a[2];
#pragma unroll
      for (int mt = 0; mt < 2; mt++)
        a[mt] = *(const bf16x8*)&sS[(mt * 16 + l16) * PS2 + kb];
#pragma unroll
      for (int j = 0; j < 2; j++) {
        bf16x8 bfr = *(const bf16x8*)&W1b[(long)(hf * 256 + w * 32 + j * 16 + l16) * DM + kb];
#pragma unroll
        for (int mt = 0; mt < 2; mt++)
          acc[mt][j] = __builtin_amdgcn_mfma_f32_16x16x32_bf16(a[mt], bfr, acc[mt][j], 0, 0, 0);
      }
    }

    // gelu -> sH (cols w*32 + j*16 + l16); x/(1+e) via v_rcp
#pragma unroll
    for (int j = 0; j < 2; j++) {
      int fl = w * 32 + j * 16 + l16;       // local col in sH
      float b1v = b1[hf * 256 + fl];
#pragma unroll
      for (int mt = 0; mt < 2; mt++)
#pragma unroll
        for (int r = 0; r < 4; r++) {
          float x = acc[mt][j][r] + b1v;
          float u = x * (0.7978845608f + 0.0356774081f * x * x);
          float e = __expf(-2.0f * u);
          float g = x * __builtin_amdgcn_rcpf(1.0f + e);
          int m = mt * 16 + half * 4 + r;
          sH[m * PHH + fl] = (__bf16)g;
        }
    }
    __syncthreads();   // sH(half hf) ready

    // ---- FF2 partial: acc2 += H @ W2^T over k = hf*256 .. hf*256+255
#pragma unroll 2
    for (int kt = 0; kt < 8; kt++) {
      int kb = kt * 32 + half * 8;
      bf16x8 a[2];
#pragma unroll
      for (int mt = 0; mt < 2; mt++)
        a[mt] = *(const bf16x8*)&sH[(mt * 16 + l16) * PHH + kb];
#pragma unroll
      for (int j = 0; j < 2; j++) {
        bf16x8 bfr = *(const bf16x8*)&W2b[(long)(n2 + j * 16 + l16) * DFF + hf * 256 + kb];
#pragma unroll
        for (int mt = 0; mt < 2; mt++)
          acc2[mt][j] = __builtin_amdgcn_mfma_f32_16x16x32_bf16(a[mt], bfr, acc2[mt][j], 0, 0, 0);
      }
    }
  }

  // epilogue: residual (re-read raw P, re-apply BN) + bias, store, fused stats
  {
#pragma unroll
    for (int j = 0; j < 2; j++) {
      int d = n2 + j * 16 + l16;
      float b2v = b2[d];
      float sc = ss[d], sh = ss[DM + d];
      float s = 0.f, s2 = 0.f;
#pragma unroll
      for (int mt = 0; mt < 2; mt++)
#pragma unroll
        for (int r = 0; r < 4; r++) {
          int m = mt * 16 + half * 4 + r;
          long idx = (row0 + m) * DM + d;
          float vv = fmaf(P[idx], sc, sh) + acc2[mt][j][r] + b2v;
          Out[idx] = vv;
          s += vv;
          s2 += vv * vv;
        }
      s  += __shfl_xor(s, 16);  s  += __shfl_xor(s, 32);
      s2 += __shfl_xor(s2, 16); s2 += __shfl_xor(s2, 32);
      if (half == 0) {
        atomicAdd(&stats[d], (double)s);
        atomicAdd(&stats[DM + d], (double)s2);
      }
    }
  }
}

extern "C" void kernel_launch(void* const* d_in, const int* in_sizes, int n_in,
                              void* d_out, int out_size, void* d_ws, size_t ws_size,
                              hipStream_t stream) {
  const float* xr  = (const float*)d_in[0];
  const float* xi  = (const float*)d_in[1];
  const float* Wre = (const float*)d_in[2];
  const float* Wim = (const float*)d_in[3];
  const float* bre = (const float*)d_in[4];
  const float* bim = (const float*)d_in[5];
  const float* W1  = (const float*)d_in[6];
  const float* b1  = (const float*)d_in[7];
  const float* W2  = (const float*)d_in[8];
  const float* b2  = (const float*)d_in[9];
  const float* g1  = (const float*)d_in[10];
  const float* be1 = (const float*)d_in[11];
  const float* g2  = (const float*)d_in[12];
  const float* be2 = (const float*)d_in[13];

  float* A = (float*)d_ws;
  double* stats = (double*)((char*)d_ws + (size_t)NELEM * 4);
  float* ss = (float*)(stats + 512);
  __bf16* W1b = (__bf16*)(ss + 512);
  __bf16* W2b = W1b + 3L * DFF * DM;
  float* T = (float*)d_out;
  __bf16* Wb = (__bf16*)d_out;   // scratch: used only before first k_attn

  k_wemb<<<512, 256, 0, stream>>>(Wre, Wim, Wb);
  k_wcvt<<<768, 256, 0, stream>>>(W1, W2, W1b, W2b);
  k_zero<<<1, 512, 0, stream>>>(stats);
  k_ident<<<1, 256, 0, stream>>>(ss);
  k_embm<<<ROWS_RE / 32, 512, 0, stream>>>(xr, xi, Wb, bre, bim, A);

  for (int l = 0; l < 3; l++) {
    // T = norm_prev(A) + attn(norm_prev(A))   (ss = identity for l==0)
    k_attn<<<dim3(27, 8, 64), dim3(32, 8), 0, stream>>>(A, ss, T);
    // BN1 stats over T
    k_bnstats<<<862, 256, 0, stream>>>(T, stats);
    k_finalize<<<1, 256, 0, stream>>>(stats, g1 + l * DM, be1 + l * DM, ss);
    // A = bn1(T) + FF(bn1(T)); BN2 stats accumulated into (re-zeroed) stats
    k_ffm<<<ROWS_ALL / 32, 512, 0, stream>>>(T, ss,
                                             W1b + (long)l * DFF * DM, b1 + l * DFF,
                                             W2b + (long)l * DFF * DM, b2 + l * DM,
                                             A, stats);
    k_finalize<<<1, 256, 0, stream>>>(stats, g2 + l * DM, be2 + l * DM, ss);
    if (l == 2) {
      k_bnfinal<<<ROWS_RE * DM / 256, 256, 0, stream>>>(A, ss, (float*)d_out);
    }
    // for l<2: next k_attn applies ss (BN2) on read of A
  }
}

// Round 7
// 1215.443 us; speedup vs baseline: 1.2606x; 1.2606x over previous
//
#include <hip/hip_runtime.h>
#include <hip/hip_bf16.h>
#include <math.h>

#define BB   64
#define CC   862
#define FB   257
#define DM   256
#define DFF  512
#define NIMG 128
#define ROWS_RE (BB*CC)        // 55168
#define ROWS_ALL (NIMG*CC)     // 110336
#define NELEM ((long)ROWS_ALL*DM)  // 28,246,016

typedef __bf16 bf16x8 __attribute__((ext_vector_type(8)));
typedef float  f32x4  __attribute__((ext_vector_type(4)));

// ---------------- FF weights f32 -> bf16, once ------------------------------
__global__ __launch_bounds__(256) void k_wcvt(const float* __restrict__ W1,
                                              const float* __restrict__ W2,
                                              __bf16* __restrict__ W1b,
                                              __bf16* __restrict__ W2b) {
  long i = ((long)blockIdx.x * 256 + threadIdx.x) * 4;
  const long N1 = 3L * DFF * DM;   // 393216
  const float* src;
  __bf16* dst;
  if (i < N1) { src = W1 + i; dst = W1b + i; }
  else        { src = W2 + (i - N1); dst = W2b + (i - N1); }
  float4 x = *(const float4*)src;
  dst[0] = (__bf16)x.x; dst[1] = (__bf16)x.y;
  dst[2] = (__bf16)x.z; dst[3] = (__bf16)x.w;
}

// stats zero + identity ss in one launch
__global__ void k_init(double* __restrict__ stats, float* __restrict__ ss) {
  int t = threadIdx.x;          // 0..511
  stats[t] = 0.0;
  if (t < 256) { ss[t] = 1.0f; ss[DM + t] = 0.0f; }
}

// ---------------- embedding weights -> bf16 B matrix [512][544] -------------
#define KE 544
#define PE 552

__global__ __launch_bounds__(256) void k_wemb(const float* __restrict__ Wre,
                                              const float* __restrict__ Wim,
                                              __bf16* __restrict__ Wb) {
  int n = blockIdx.x;          // 0..511
  int d = n & 255;
  bool im = (n >= 256);
  const float* Wa = im ? Wim : Wre;   // k<257 part
  const float* Wc = im ? Wre : Wim;   // k>=257 part
  float sgn = im ? 1.0f : -1.0f;
  for (int k = threadIdx.x; k < KE; k += 256) {
    float v;
    if (k < 257)      v = Wa[(long)d * FB + k];
    else if (k < 514) v = sgn * Wc[(long)d * FB + (k - 257)];
    else              v = 0.0f;
    Wb[(long)n * KE + k] = (__bf16)v;
  }
}

// ---------------- embedding as bf16 MFMA GEMM (R5 config) --------------------
// 32 rows/block, 4 waves; wave w owns output cols [w*128,(w+1)*128).
// LDS 32*552*2 = 34.5KB -> 4 blocks/CU -> 4 waves/SIMD.
__global__ __launch_bounds__(256, 4) void k_embm(
    const float* __restrict__ xr, const float* __restrict__ xi,
    const __bf16* __restrict__ Wb,
    const float* __restrict__ bre, const float* __restrict__ bim,
    float* __restrict__ A) {
  __shared__ __bf16 sA[32 * PE];
  int t = threadIdx.x;
  int lane = t & 63;
  int w = t >> 6;           // 0..3
  int half = lane >> 4;     // 0..3
  int l16 = lane & 15;
  long row0 = (long)blockIdx.x * 32;

  // zero K-pad [514,544)
  for (int idx = t; idx < 32 * 30; idx += 256) {
    int r = idx / 30, j = idx - r * 30;
    sA[r * PE + 514 + j] = (__bf16)0.f;
  }
  // stage x tile: f32 -> bf16, xr at k<257, xi at 257+f
  for (int idx = t; idx < 32 * 257; idx += 256) {
    int r = idx / 257, f = idx - r * 257;
    long g = (row0 + r) * FB + f;
    sA[r * PE + f]       = (__bf16)xr[g];
    sA[r * PE + 257 + f] = (__bf16)xi[g];
  }
  __syncthreads();

  int n0 = w * 128;
  f32x4 acc[2][8];
#pragma unroll
  for (int mt = 0; mt < 2; mt++)
#pragma unroll
    for (int j = 0; j < 8; j++) acc[mt][j] = (f32x4){0.f, 0.f, 0.f, 0.f};

#pragma unroll 1
  for (int kt = 0; kt < 17; kt++) {
    int kb = kt * 32 + half * 8;
    bf16x8 a[2];
#pragma unroll
    for (int mt = 0; mt < 2; mt++)
      a[mt] = *(const bf16x8*)&sA[(mt * 16 + l16) * PE + kb];
#pragma unroll
    for (int j = 0; j < 8; j++) {
      bf16x8 bfr = *(const bf16x8*)&Wb[(long)(n0 + j * 16 + l16) * KE + kb];
#pragma unroll
      for (int mt = 0; mt < 2; mt++)
        acc[mt][j] = __builtin_amdgcn_mfma_f32_16x16x32_bf16(a[mt], bfr, acc[mt][j], 0, 0, 0);
    }
  }

  // epilogue: bias + store f32 (re half / im half of A)
#pragma unroll
  for (int j = 0; j < 8; j++) {
    int n = n0 + j * 16 + l16;
    int d = n & 255;
    float bv = (n < 256) ? bre[d] : bim[d];
    long rbase = (n < 256) ? 0L : (long)ROWS_RE;
#pragma unroll
    for (int mt = 0; mt < 2; mt++)
#pragma unroll
      for (int r = 0; r < 4; r++) {
        int m = mt * 16 + half * 4 + r;
        A[(row0 + m + rbase) * DM + d] = acc[mt][j][r] + bv;
      }
  }
}

// ---------------- attention + fused BN-apply on read + transpose-scramble ----
__global__ __launch_bounds__(256) void k_attn(const float* __restrict__ A,
                                              const float* __restrict__ ss,
                                              float* __restrict__ T) {
  __shared__ float ore[32][33];
  __shared__ float oim[32][33];
  __shared__ float ssc[256];
  __shared__ float ssh[256];
  int tx = threadIdx.x;
  int ty = threadIdx.y;
  int t = ty * 32 + tx;
  ssc[t] = ss[t];
  ssh[t] = ss[DM + t];
  __syncthreads();

  int c0 = blockIdx.x * 32;
  int d0 = blockIdx.y * 32;
  int b  = blockIdx.z;
  const long base_re = (long)b * CC * DM;
  const long base_im = (long)(b + BB) * CC * DM;
  int d = d0 + tx;
  int kd = DM - 1 - d;
  float scq = ssc[d], shq = ssh[d];
  float sck = ssc[kd], shk = ssh[kd];
#pragma unroll
  for (int q = 0; q < 4; q++) {
    int cl = ty + 8 * q;
    int c = c0 + cl;
    if (c < CC) {
      float qr = fmaf(A[base_re + (long)c * DM + d], scq, shq);
      float qi = fmaf(A[base_im + (long)c * DM + d], scq, shq);
      float kr = fmaf(A[base_re + (long)(CC - 1 - c) * DM + kd], sck, shk);
      float ki = fmaf(A[base_im + (long)(CC - 1 - c) * DM + kd], sck, shk);
      float asr = 0.25f * (qr * kr - qi * ki);
      float asi = 0.25f * (qr * ki - qi * kr);
      ore[cl][tx] = (asr - asi) * qr;
      oim[cl][tx] = (asr + asi) * qr;
    }
  }
  __syncthreads();
#pragma unroll
  for (int q = 0; q < 4; q++) {
    int dl = ty + 8 * q;
    int dd = d0 + dl;
    int c = c0 + tx;
    if (c < CC) {
      long flat = (long)dd * CC + c;
      int dp = (int)(flat & 255);
      float sc = ssc[dp], sh = ssh[dp];
      T[base_re + flat] = fmaf(A[base_re + flat], sc, sh) + ore[tx][dl];
      T[base_im + flat] = fmaf(A[base_im + flat], sc, sh) + oim[tx][dl];
    }
  }
}

// ---------------- batchnorm helpers ----------------
__global__ __launch_bounds__(256) void k_bnstats(const float* __restrict__ P,
                                                 double* __restrict__ stats) {
  int d = threadIdx.x;
  long row0 = (long)blockIdx.x * 128;
  double s = 0.0, s2 = 0.0;
  for (int r = 0; r < 128; r++) {
    float x = P[(row0 + r) * DM + d];
    s += (double)x;
    s2 += (double)x * (double)x;
  }
  atomicAdd(&stats[d], s);
  atomicAdd(&stats[DM + d], s2);
}

// finalize + re-zero stats for the next accumulation pass
__global__ void k_finalize(double* __restrict__ stats,
                           const float* __restrict__ g, const float* __restrict__ be,
                           float* __restrict__ ss) {
  int d = threadIdx.x;
  double n = (double)ROWS_ALL;
  double m = stats[d] / n;
  double v = stats[DM + d] / n - m * m;
  float inv = (float)(1.0 / sqrt(v + 1e-5));
  float sc = g[d] * inv;
  ss[d] = sc;
  ss[DM + d] = be[d] - (float)m * sc;
  stats[d] = 0.0;
  stats[DM + d] = 0.0;
}

__global__ __launch_bounds__(256) void k_bnfinal(const float* __restrict__ A,
                                                 const float* __restrict__ ss,
                                                 float* __restrict__ out) {
  long gid = (long)blockIdx.x * 256 + threadIdx.x;
  int d = (int)(gid & 255);
  long bc = gid >> 8;
  float sc = ss[d], sh = ss[DM + d];
  float re = A[bc * DM + d];
  float im = A[(bc + (long)ROWS_RE) * DM + d];
  float2 o;
  o.x = fmaf(re, sc, sh);
  o.y = fmaf(im, sc, sh);
  ((float2*)out)[gid] = o;
}

// ---------------- MFMA fused FF v6 ------------------------------------------
// out = bn(src) + gelu(bn(src)@W1^T + b1)@W2^T + b2, plus atomic BN-stats of out.
// v6: 64 rows/block, 8 waves, F in FOUR chunks of 128 sharing one 64x132 H
// buffer. LDS 34.3 + 16.9 = 51.2KB -> 3 blocks/CU (6 waves/SIMD), VGPR ~64
// (same budget as R5's 182us config). Per-block weight traffic unchanged
// (each W1/W2 element read once). FF2 K-order identical to R5 (k ascending).
#define PS2 268
#define PH4 132

__global__ __launch_bounds__(512, 4) void k_ffm(
    const float* __restrict__ P, const float* __restrict__ ss,
    const __bf16* __restrict__ W1b, const float* __restrict__ b1,
    const __bf16* __restrict__ W2b, const float* __restrict__ b2,
    float* __restrict__ Out, double* __restrict__ stats) {
  __shared__ __bf16 sS[64 * PS2];
  __shared__ __bf16 sH[64 * PH4];
  int t = threadIdx.x;
  int lane = t & 63;
  int w = t >> 6;           // 0..7
  int half = lane >> 4;     // 0..3
  int l16 = lane & 15;
  long row0 = (long)blockIdx.x * 64;

  // ---- stage S tile: f32 -> BN-apply -> bf16 ----
  {
    const float4* Pv = (const float4*)(P + row0 * DM);
    const float4* scv = (const float4*)ss;
    const float4* shv = (const float4*)(ss + DM);
#pragma unroll
    for (int i = 0; i < 8; i++) {
      int v = t + i * 512;        // 4096 float4s = 64 rows x 64
      int r = v >> 6, k4 = v & 63;
      float4 x = Pv[(long)r * 64 + k4];
      float4 sc = scv[k4];
      float4 sh = shv[k4];
      x.x = fmaf(x.x, sc.x, sh.x);
      x.y = fmaf(x.y, sc.y, sh.y);
      x.z = fmaf(x.z, sc.z, sh.z);
      x.w = fmaf(x.w, sc.w, sh.w);
      __bf16* dst = &sS[r * PS2 + k4 * 4];
      dst[0] = (__bf16)x.x; dst[1] = (__bf16)x.y;
      dst[2] = (__bf16)x.z; dst[3] = (__bf16)x.w;
    }
  }
  __syncthreads();

  int n2 = w * 32;
  f32x4 acc2[4][2];
#pragma unroll
  for (int mt = 0; mt < 4; mt++)
#pragma unroll
    for (int j = 0; j < 2; j++) acc2[mt][j] = (f32x4){0.f, 0.f, 0.f, 0.f};

#pragma unroll 1
  for (int q = 0; q < 4; q++) {
    if (q > 0) __syncthreads();   // all waves done reading sH(chunk q-1)

    // ---- FF1 chunk: H[:, q*128 + w*16 + l16] = gelu(S @ W1^T + b1), K=256
    f32x4 acc[4];
#pragma unroll
    for (int mt = 0; mt < 4; mt++) acc[mt] = (f32x4){0.f, 0.f, 0.f, 0.f};

#pragma unroll 2
    for (int kt = 0; kt < 8; kt++) {
      int kb = kt * 32 + half * 8;
      bf16x8 a[4];
#pragma unroll
      for (int mt = 0; mt < 4; mt++)
        a[mt] = *(const bf16x8*)&sS[(mt * 16 + l16) * PS2 + kb];
      bf16x8 bfr = *(const bf16x8*)&W1b[(long)(q * 128 + w * 16 + l16) * DM + kb];
#pragma unroll
      for (int mt = 0; mt < 4; mt++)
        acc[mt] = __builtin_amdgcn_mfma_f32_16x16x32_bf16(a[mt], bfr, acc[mt], 0, 0, 0);
    }

    // gelu -> sH (local col fl = w*16 + l16); x/(1+e) via v_rcp
    {
      int fl = w * 16 + l16;
      float b1v = b1[q * 128 + fl];
#pragma unroll
      for (int mt = 0; mt < 4; mt++)
#pragma unroll
        for (int r = 0; r < 4; r++) {
          float x = acc[mt][r] + b1v;
          float u = x * (0.7978845608f + 0.0356774081f * x * x);
          float e = __expf(-2.0f * u);
          float g = x * __builtin_amdgcn_rcpf(1.0f + e);
          int m = mt * 16 + half * 4 + r;
          sH[m * PH4 + fl] = (__bf16)g;
        }
    }
    __syncthreads();   // sH(chunk q) ready

    // ---- FF2 partial: acc2 += H @ W2^T over k = q*128 .. q*128+127
#pragma unroll 2
    for (int kt = 0; kt < 4; kt++) {
      int kb = kt * 32 + half * 8;
      bf16x8 a[4];
#pragma unroll
      for (int mt = 0; mt < 4; mt++)
        a[mt] = *(const bf16x8*)&sH[(mt * 16 + l16) * PH4 + kb];
#pragma unroll
      for (int j = 0; j < 2; j++) {
        bf16x8 bfr = *(const bf16x8*)&W2b[(long)(n2 + j * 16 + l16) * DFF + q * 128 + kb];
#pragma unroll
        for (int mt = 0; mt < 4; mt++)
          acc2[mt][j] = __builtin_amdgcn_mfma_f32_16x16x32_bf16(a[mt], bfr, acc2[mt][j], 0, 0, 0);
      }
    }
  }

  // epilogue: residual (re-read raw P, re-apply BN) + bias, store, fused stats
  {
#pragma unroll
    for (int j = 0; j < 2; j++) {
      int d = n2 + j * 16 + l16;
      float b2v = b2[d];
      float sc = ss[d], sh = ss[DM + d];
      float s = 0.f, s2 = 0.f;
#pragma unroll
      for (int mt = 0; mt < 4; mt++)
#pragma unroll
        for (int r = 0; r < 4; r++) {
          int m = mt * 16 + half * 4 + r;
          long idx = (row0 + m) * DM + d;
          float vv = fmaf(P[idx], sc, sh) + acc2[mt][j][r] + b2v;
          Out[idx] = vv;
          s += vv;
          s2 += vv * vv;
        }
      s  += __shfl_xor(s, 16);  s  += __shfl_xor(s, 32);
      s2 += __shfl_xor(s2, 16); s2 += __shfl_xor(s2, 32);
      if (half == 0) {
        atomicAdd(&stats[d], (double)s);
        atomicAdd(&stats[DM + d], (double)s2);
      }
    }
  }
}

extern "C" void kernel_launch(void* const* d_in, const int* in_sizes, int n_in,
                              void* d_out, int out_size, void* d_ws, size_t ws_size,
                              hipStream_t stream) {
  const float* xr  = (const float*)d_in[0];
  const float* xi  = (const float*)d_in[1];
  const float* Wre = (const float*)d_in[2];
  const float* Wim = (const float*)d_in[3];
  const float* bre = (const float*)d_in[4];
  const float* bim = (const float*)d_in[5];
  const float* W1  = (const float*)d_in[6];
  const float* b1  = (const float*)d_in[7];
  const float* W2  = (const float*)d_in[8];
  const float* b2  = (const float*)d_in[9];
  const float* g1  = (const float*)d_in[10];
  const float* be1 = (const float*)d_in[11];
  const float* g2  = (const float*)d_in[12];
  const float* be2 = (const float*)d_in[13];

  float* A = (float*)d_ws;
  double* stats = (double*)((char*)d_ws + (size_t)NELEM * 4);
  float* ss = (float*)(stats + 512);
  __bf16* W1b = (__bf16*)(ss + 512);
  __bf16* W2b = W1b + 3L * DFF * DM;
  float* T = (float*)d_out;
  __bf16* Wb = (__bf16*)d_out;   // scratch: used only before first k_attn

  k_wemb<<<512, 256, 0, stream>>>(Wre, Wim, Wb);
  k_wcvt<<<768, 256, 0, stream>>>(W1, W2, W1b, W2b);
  k_init<<<1, 512, 0, stream>>>(stats, ss);
  k_embm<<<ROWS_RE / 32, 256, 0, stream>>>(xr, xi, Wb, bre, bim, A);

  for (int l = 0; l < 3; l++) {
    // T = norm_prev(A) + attn(norm_prev(A))   (ss = identity for l==0)
    k_attn<<<dim3(27, 8, 64), dim3(32, 8), 0, stream>>>(A, ss, T);
    // BN1 stats over T
    k_bnstats<<<862, 256, 0, stream>>>(T, stats);
    k_finalize<<<1, 256, 0, stream>>>(stats, g1 + l * DM, be1 + l * DM, ss);
    // A = bn1(T) + FF(bn1(T)); BN2 stats accumulated into (re-zeroed) stats
    k_ffm<<<ROWS_ALL / 64, 512, 0, stream>>>(T, ss,
                                             W1b + (long)l * DFF * DM, b1 + l * DFF,
                                             W2b + (long)l * DFF * DM, b2 + l * DM,
                                             A, stats);
    k_finalize<<<1, 256, 0, stream>>>(stats, g2 + l * DM, be2 + l * DM, ss);
    if (l == 2) {
      k_bnfinal<<<ROWS_RE * DM / 256, 256, 0, stream>>>(A, ss, (float*)d_out);
    }
    // for l<2: next k_attn applies ss (BN2) on read of A
  }
}

// Round 8
// 1188.059 us; speedup vs baseline: 1.2897x; 1.0230x over previous
//
#include <hip/hip_runtime.h>
#include <hip/hip_bf16.h>
#include <math.h>

#define BB   64
#define CC   862
#define FB   257
#define DM   256
#define DFF  512
#define NIMG 128
#define ROWS_RE (BB*CC)        // 55168
#define ROWS_ALL (NIMG*CC)     // 110336
#define NELEM ((long)ROWS_ALL*DM)  // 28,246,016

typedef __bf16 bf16x8 __attribute__((ext_vector_type(8)));
typedef float  f32x4  __attribute__((ext_vector_type(4)));
typedef float  f32x16 __attribute__((ext_vector_type(16)));

// ---------------- FF weights f32 -> bf16, once ------------------------------
__global__ __launch_bounds__(256) void k_wcvt(const float* __restrict__ W1,
                                              const float* __restrict__ W2,
                                              __bf16* __restrict__ W1b,
                                              __bf16* __restrict__ W2b) {
  long i = ((long)blockIdx.x * 256 + threadIdx.x) * 4;
  const long N1 = 3L * DFF * DM;   // 393216
  const float* src;
  __bf16* dst;
  if (i < N1) { src = W1 + i; dst = W1b + i; }
  else        { src = W2 + (i - N1); dst = W2b + (i - N1); }
  float4 x = *(const float4*)src;
  dst[0] = (__bf16)x.x; dst[1] = (__bf16)x.y;
  dst[2] = (__bf16)x.z; dst[3] = (__bf16)x.w;
}

// stats zero + identity ss in one launch
__global__ void k_init(double* __restrict__ stats, float* __restrict__ ss) {
  int t = threadIdx.x;          // 0..511
  stats[t] = 0.0;
  if (t < 256) { ss[t] = 1.0f; ss[DM + t] = 0.0f; }
}

// ---------------- embedding weights -> bf16 B matrix [512][544] -------------
#define KE 544
#define PE 552

__global__ __launch_bounds__(256) void k_wemb(const float* __restrict__ Wre,
                                              const float* __restrict__ Wim,
                                              __bf16* __restrict__ Wb) {
  int n = blockIdx.x;          // 0..511
  int d = n & 255;
  bool im = (n >= 256);
  const float* Wa = im ? Wim : Wre;   // k<257 part
  const float* Wc = im ? Wre : Wim;   // k>=257 part
  float sgn = im ? 1.0f : -1.0f;
  for (int k = threadIdx.x; k < KE; k += 256) {
    float v;
    if (k < 257)      v = Wa[(long)d * FB + k];
    else if (k < 514) v = sgn * Wc[(long)d * FB + (k - 257)];
    else              v = 0.0f;
    Wb[(long)n * KE + k] = (__bf16)v;
  }
}

// ---------------- embedding as bf16 MFMA GEMM -------------------------------
// 32 rows/block, 4 waves; wave w owns output cols [w*128,(w+1)*128).
// LDS 32*552*2 = 34.5KB -> 4 blocks/CU -> 4 waves/SIMD.
__global__ __launch_bounds__(256, 4) void k_embm(
    const float* __restrict__ xr, const float* __restrict__ xi,
    const __bf16* __restrict__ Wb,
    const float* __restrict__ bre, const float* __restrict__ bim,
    float* __restrict__ A) {
  __shared__ __bf16 sA[32 * PE];
  int t = threadIdx.x;
  int lane = t & 63;
  int w = t >> 6;           // 0..3
  int half = lane >> 4;     // 0..3
  int l16 = lane & 15;
  long row0 = (long)blockIdx.x * 32;

  // zero K-pad [514,544)
  for (int idx = t; idx < 32 * 30; idx += 256) {
    int r = idx / 30, j = idx - r * 30;
    sA[r * PE + 514 + j] = (__bf16)0.f;
  }
  // stage x tile: f32 -> bf16, xr at k<257, xi at 257+f
  for (int idx = t; idx < 32 * 257; idx += 256) {
    int r = idx / 257, f = idx - r * 257;
    long g = (row0 + r) * FB + f;
    sA[r * PE + f]       = (__bf16)xr[g];
    sA[r * PE + 257 + f] = (__bf16)xi[g];
  }
  __syncthreads();

  int n0 = w * 128;
  f32x4 acc[2][8];
#pragma unroll
  for (int mt = 0; mt < 2; mt++)
#pragma unroll
    for (int j = 0; j < 8; j++) acc[mt][j] = (f32x4){0.f, 0.f, 0.f, 0.f};

#pragma unroll 1
  for (int kt = 0; kt < 17; kt++) {
    int kb = kt * 32 + half * 8;
    bf16x8 a[2];
#pragma unroll
    for (int mt = 0; mt < 2; mt++)
      a[mt] = *(const bf16x8*)&sA[(mt * 16 + l16) * PE + kb];
#pragma unroll
    for (int j = 0; j < 8; j++) {
      bf16x8 bfr = *(const bf16x8*)&Wb[(long)(n0 + j * 16 + l16) * KE + kb];
#pragma unroll
      for (int mt = 0; mt < 2; mt++)
        acc[mt][j] = __builtin_amdgcn_mfma_f32_16x16x32_bf16(a[mt], bfr, acc[mt][j], 0, 0, 0);
    }
  }

  // epilogue: bias + store f32 (re half / im half of A)
#pragma unroll
  for (int j = 0; j < 8; j++) {
    int n = n0 + j * 16 + l16;
    int d = n & 255;
    float bv = (n < 256) ? bre[d] : bim[d];
    long rbase = (n < 256) ? 0L : (long)ROWS_RE;
#pragma unroll
    for (int mt = 0; mt < 2; mt++)
#pragma unroll
      for (int r = 0; r < 4; r++) {
        int m = mt * 16 + half * 4 + r;
        A[(row0 + m + rbase) * DM + d] = acc[mt][j][r] + bv;
      }
  }
}

// ---------------- attention + fused BN-apply on read + transpose-scramble ----
__global__ __launch_bounds__(256) void k_attn(const float* __restrict__ A,
                                              const float* __restrict__ ss,
                                              float* __restrict__ T) {
  __shared__ float ore[32][33];
  __shared__ float oim[32][33];
  __shared__ float ssc[256];
  __shared__ float ssh[256];
  int tx = threadIdx.x;
  int ty = threadIdx.y;
  int t = ty * 32 + tx;
  ssc[t] = ss[t];
  ssh[t] = ss[DM + t];
  __syncthreads();

  int c0 = blockIdx.x * 32;
  int d0 = blockIdx.y * 32;
  int b  = blockIdx.z;
  const long base_re = (long)b * CC * DM;
  const long base_im = (long)(b + BB) * CC * DM;
  int d = d0 + tx;
  int kd = DM - 1 - d;
  float scq = ssc[d], shq = ssh[d];
  float sck = ssc[kd], shk = ssh[kd];
#pragma unroll
  for (int q = 0; q < 4; q++) {
    int cl = ty + 8 * q;
    int c = c0 + cl;
    if (c < CC) {
      float qr = fmaf(A[base_re + (long)c * DM + d], scq, shq);
      float qi = fmaf(A[base_im + (long)c * DM + d], scq, shq);
      float kr = fmaf(A[base_re + (long)(CC - 1 - c) * DM + kd], sck, shk);
      float ki = fmaf(A[base_im + (long)(CC - 1 - c) * DM + kd], sck, shk);
      float asr = 0.25f * (qr * kr - qi * ki);
      float asi = 0.25f * (qr * ki - qi * kr);
      ore[cl][tx] = (asr - asi) * qr;
      oim[cl][tx] = (asr + asi) * qr;
    }
  }
  __syncthreads();
#pragma unroll
  for (int q = 0; q < 4; q++) {
    int dl = ty + 8 * q;
    int dd = d0 + dl;
    int c = c0 + tx;
    if (c < CC) {
      long flat = (long)dd * CC + c;
      int dp = (int)(flat & 255);
      float sc = ssc[dp], sh = ssh[dp];
      T[base_re + flat] = fmaf(A[base_re + flat], sc, sh) + ore[tx][dl];
      T[base_im + flat] = fmaf(A[base_im + flat], sc, sh) + oim[tx][dl];
    }
  }
}

// ---------------- batchnorm helpers ----------------
__global__ __launch_bounds__(256) void k_bnstats(const float* __restrict__ P,
                                                 double* __restrict__ stats) {
  int d = threadIdx.x;
  long row0 = (long)blockIdx.x * 128;
  double s = 0.0, s2 = 0.0;
  for (int r = 0; r < 128; r++) {
    float x = P[(row0 + r) * DM + d];
    s += (double)x;
    s2 += (double)x * (double)x;
  }
  atomicAdd(&stats[d], s);
  atomicAdd(&stats[DM + d], s2);
}

// finalize + re-zero stats for the next accumulation pass
__global__ void k_finalize(double* __restrict__ stats,
                           const float* __restrict__ g, const float* __restrict__ be,
                           float* __restrict__ ss) {
  int d = threadIdx.x;
  double n = (double)ROWS_ALL;
  double m = stats[d] / n;
  double v = stats[DM + d] / n - m * m;
  float inv = (float)(1.0 / sqrt(v + 1e-5));
  float sc = g[d] * inv;
  ss[d] = sc;
  ss[DM + d] = be[d] - (float)m * sc;
  stats[d] = 0.0;
  stats[DM + d] = 0.0;
}

__global__ __launch_bounds__(256) void k_bnfinal(const float* __restrict__ A,
                                                 const float* __restrict__ ss,
                                                 float* __restrict__ out) {
  long gid = (long)blockIdx.x * 256 + threadIdx.x;
  int d = (int)(gid & 255);
  long bc = gid >> 8;
  float sc = ss[d], sh = ss[DM + d];
  float re = A[bc * DM + d];
  float im = A[(bc + (long)ROWS_RE) * DM + d];
  float2 o;
  o.x = fmaf(re, sc, sh);
  o.y = fmaf(im, sc, sh);
  ((float2*)out)[gid] = o;
}

// ---------------- MFMA fused FF v7: 32x32x16 --------------------------------
// out = bn(src) + gelu(bn(src)@W1^T + b1)@W2^T + b2, plus atomic BN-stats.
// 64 rows/block, 8 waves, F in two halves of 256 sharing one 64x260 H buffer.
// 32x32x16 MFMA: same fragment bytes per instr as 16x16x32 but 2x FLOP ->
// halves ds_read_b128 count (the dominant pipe, ~40% est from instr model).
// Wave w owns output cols [w*32,(w+1)*32) (FF1 per half, FF2), computes BOTH
// 32-row M-tiles -> each weight element still read once per block.
// C/D layout (m74/m101): col=lane&31, row=(reg&3)+8*(reg>>2)+4*(lane>>5).
// A/B: row/col=lane&31, k=(lane>>5)*8+e.
// LDS 34.3+33.3=67.6KB -> 2 blocks/CU; VGPR ~100 -> 4 waves/SIMD.
#define PS2 268   // 134 dw = 6 mod 32 -> 32-row b128 reads 2-way (free)
#define PH2 260   // 130 dw = 2 mod 32 -> 32-row b128 reads 2-way (free)

__global__ __launch_bounds__(512, 4) void k_ffm(
    const float* __restrict__ P, const float* __restrict__ ss,
    const __bf16* __restrict__ W1b, const float* __restrict__ b1,
    const __bf16* __restrict__ W2b, const float* __restrict__ b2,
    float* __restrict__ Out, double* __restrict__ stats) {
  __shared__ __bf16 sS[64 * PS2];
  __shared__ __bf16 sH[64 * PH2];
  int t = threadIdx.x;
  int lane = t & 63;
  int w = t >> 6;           // 0..7
  int hi = lane >> 5;       // 0..1  (k-group)
  int l32 = lane & 31;
  long row0 = (long)blockIdx.x * 64;

  // ---- stage S tile: f32 -> BN-apply -> bf16 ----
  {
    const float4* Pv = (const float4*)(P + row0 * DM);
    const float4* scv = (const float4*)ss;
    const float4* shv = (const float4*)(ss + DM);
#pragma unroll
    for (int i = 0; i < 8; i++) {
      int v = t + i * 512;        // 4096 float4s = 64 rows x 64
      int r = v >> 6, k4 = v & 63;
      float4 x = Pv[(long)r * 64 + k4];
      float4 sc = scv[k4];
      float4 sh = shv[k4];
      x.x = fmaf(x.x, sc.x, sh.x);
      x.y = fmaf(x.y, sc.y, sh.y);
      x.z = fmaf(x.z, sc.z, sh.z);
      x.w = fmaf(x.w, sc.w, sh.w);
      __bf16* dst = &sS[r * PS2 + k4 * 4];
      dst[0] = (__bf16)x.x; dst[1] = (__bf16)x.y;
      dst[2] = (__bf16)x.z; dst[3] = (__bf16)x.w;
    }
  }
  __syncthreads();

  f32x16 acc2[2];
#pragma unroll
  for (int mt = 0; mt < 2; mt++)
#pragma unroll
    for (int r = 0; r < 16; r++) acc2[mt][r] = 0.f;

#pragma unroll 1
  for (int hf = 0; hf < 2; hf++) {
    if (hf == 1) __syncthreads();   // all waves done reading sH(half 0)

    // ---- FF1 half: H[:, f] = gelu(S @ W1^T + b1), f = hf*256 + w*32 + l32
    f32x16 acc1[2];
#pragma unroll
    for (int mt = 0; mt < 2; mt++)
#pragma unroll
      for (int r = 0; r < 16; r++) acc1[mt][r] = 0.f;

    const __bf16* w1row = W1b + (long)(hf * 256 + w * 32 + l32) * DM;
#pragma unroll 2
    for (int kt = 0; kt < 16; kt++) {
      int kb = kt * 16 + hi * 8;
      bf16x8 a0 = *(const bf16x8*)&sS[l32 * PS2 + kb];
      bf16x8 a1 = *(const bf16x8*)&sS[(32 + l32) * PS2 + kb];
      bf16x8 bfr = *(const bf16x8*)&w1row[kb];
      acc1[0] = __builtin_amdgcn_mfma_f32_32x32x16_bf16(a0, bfr, acc1[0], 0, 0, 0);
      acc1[1] = __builtin_amdgcn_mfma_f32_32x32x16_bf16(a1, bfr, acc1[1], 0, 0, 0);
    }

    // gelu -> sH (local col fl = w*32 + l32); x/(1+e) via v_rcp
    {
      int fl = w * 32 + l32;
      float b1v = b1[hf * 256 + fl];
#pragma unroll
      for (int mt = 0; mt < 2; mt++)
#pragma unroll
        for (int r = 0; r < 16; r++) {
          float x = acc1[mt][r] + b1v;
          float u = x * (0.7978845608f + 0.0356774081f * x * x);
          float e = __expf(-2.0f * u);
          float g = x * __builtin_amdgcn_rcpf(1.0f + e);
          int m = mt * 32 + (r & 3) + 8 * (r >> 2) + 4 * hi;
          sH[m * PH2 + fl] = (__bf16)g;
        }
    }
    __syncthreads();   // sH(half hf) ready

    // ---- FF2 partial: acc2 += H @ W2^T over k = hf*256 .. hf*256+255
    const __bf16* w2row = W2b + (long)(w * 32 + l32) * DFF + hf * 256;
#pragma unroll 2
    for (int kt = 0; kt < 16; kt++) {
      int kb = kt * 16 + hi * 8;
      bf16x8 a0 = *(const bf16x8*)&sH[l32 * PH2 + kb];
      bf16x8 a1 = *(const bf16x8*)&sH[(32 + l32) * PH2 + kb];
      bf16x8 bfr = *(const bf16x8*)&w2row[kb];
      acc2[0] = __builtin_amdgcn_mfma_f32_32x32x16_bf16(a0, bfr, acc2[0], 0, 0, 0);
      acc2[1] = __builtin_amdgcn_mfma_f32_32x32x16_bf16(a1, bfr, acc2[1], 0, 0, 0);
    }
  }

  // epilogue: residual (re-read raw P, re-apply BN) + bias, store, fused stats
  {
    int d = w * 32 + l32;
    float b2v = b2[d];
    float sc = ss[d], sh = ss[DM + d];
    float s = 0.f, s2 = 0.f;
#pragma unroll
    for (int mt = 0; mt < 2; mt++)
#pragma unroll
      for (int r = 0; r < 16; r++) {
        int m = mt * 32 + (r & 3) + 8 * (r >> 2) + 4 * hi;
        long idx = (row0 + m) * DM + d;
        float vv = fmaf(P[idx], sc, sh) + acc2[mt][r] + b2v;
        Out[idx] = vv;
        s += vv;
        s2 += vv * vv;
      }
    // lanes l32 and l32+32 share column d
    s  += __shfl_xor(s, 32);
    s2 += __shfl_xor(s2, 32);
    if (hi == 0) {
      atomicAdd(&stats[d], (double)s);
      atomicAdd(&stats[DM + d], (double)s2);
    }
  }
}

extern "C" void kernel_launch(void* const* d_in, const int* in_sizes, int n_in,
                              void* d_out, int out_size, void* d_ws, size_t ws_size,
                              hipStream_t stream) {
  const float* xr  = (const float*)d_in[0];
  const float* xi  = (const float*)d_in[1];
  const float* Wre = (const float*)d_in[2];
  const float* Wim = (const float*)d_in[3];
  const float* bre = (const float*)d_in[4];
  const float* bim = (const float*)d_in[5];
  const float* W1  = (const float*)d_in[6];
  const float* b1  = (const float*)d_in[7];
  const float* W2  = (const float*)d_in[8];
  const float* b2  = (const float*)d_in[9];
  const float* g1  = (const float*)d_in[10];
  const float* be1 = (const float*)d_in[11];
  const float* g2  = (const float*)d_in[12];
  const float* be2 = (const float*)d_in[13];

  float* A = (float*)d_ws;
  double* stats = (double*)((char*)d_ws + (size_t)NELEM * 4);
  float* ss = (float*)(stats + 512);
  __bf16* W1b = (__bf16*)(ss + 512);
  __bf16* W2b = W1b + 3L * DFF * DM;
  float* T = (float*)d_out;
  __bf16* Wb = (__bf16*)d_out;   // scratch: used only before first k_attn

  k_wemb<<<512, 256, 0, stream>>>(Wre, Wim, Wb);
  k_wcvt<<<768, 256, 0, stream>>>(W1, W2, W1b, W2b);
  k_init<<<1, 512, 0, stream>>>(stats, ss);
  k_embm<<<ROWS_RE / 32, 256, 0, stream>>>(xr, xi, Wb, bre, bim, A);

  for (int l = 0; l < 3; l++) {
    // T = norm_prev(A) + attn(norm_prev(A))   (ss = identity for l==0)
    k_attn<<<dim3(27, 8, 64), dim3(32, 8), 0, stream>>>(A, ss, T);
    // BN1 stats over T
    k_bnstats<<<862, 256, 0, stream>>>(T, stats);
    k_finalize<<<1, 256, 0, stream>>>(stats, g1 + l * DM, be1 + l * DM, ss);
    // A = bn1(T) + FF(bn1(T)); BN2 stats accumulated into (re-zeroed) stats
    k_ffm<<<ROWS_ALL / 64, 512, 0, stream>>>(T, ss,
                                             W1b + (long)l * DFF * DM, b1 + l * DFF,
                                             W2b + (long)l * DFF * DM, b2 + l * DM,
                                             A, stats);
    k_finalize<<<1, 256, 0, stream>>>(stats, g2 + l * DM, be2 + l * DM, ss);
    if (l == 2) {
      k_bnfinal<<<ROWS_RE * DM / 256, 256, 0, stream>>>(A, ss, (float*)d_out);
    }
    // for l<2: next k_attn applies ss (BN2) on read of A
  }
}